// Round 2
// baseline (1501.640 us; speedup 1.0000x reference)
//
#include <hip/hip_runtime.h>

// Problem constants (B,T,C,H,W,D) from the reference.
constexpr int B_ = 2, T_ = 2048, C_ = 1024, H_ = 16, W_ = 256, D_ = 64;
constexpr int M_ = B_ * T_;            // 4096 rows
constexpr float SCALE_ = 0.125f;       // 1/sqrt(64)

// ---------------------------------------------------------------------------
// GEMM: Y[m,n] = sum_k X[m,k] * Wt[n,k]   (x @ w.T, both row-major)
// 128x128 tile, BK=32, 256 threads, 8x8 micro-tile split as 2x2 blocks of
// 4x4 (fragments 64 apart -> all LDS reads broadcast or 2-way = free).
// LDS k-major, group-of-4 XOR swizzle. blockIdx.z selects weight/output pair.
// ---------------------------------------------------------------------------
__global__ __launch_bounds__(256, 2) void gemm_xwT(
    const float* __restrict__ X,
    const float* __restrict__ W0, const float* __restrict__ W1,
    const float* __restrict__ W2,
    float* __restrict__ Y0, float* __restrict__ Y1, float* __restrict__ Y2,
    int M, int N, int K)
{
    const float* Wm = (blockIdx.z == 0) ? W0 : (blockIdx.z == 1) ? W1 : W2;
    float*       Ym = (blockIdx.z == 0) ? Y0 : (blockIdx.z == 1) ? Y1 : Y2;

    __shared__ float As[32][128];  // [k][m], m-groups of 4 XOR-swizzled by k
    __shared__ float Bs[32][128];  // [k][n], same

    const int tid = threadIdx.x;
    const int tx = tid & 15, ty = tid >> 4;
    const int m0 = blockIdx.y * 128, n0 = blockIdx.x * 128;

    float acc[2][2][4][4] = {};    // [ih][jh][i][j]

    for (int k0 = 0; k0 < K; k0 += 32) {
        // Stage 128x32 A and B tiles, transposed to k-major with swizzle.
#pragma unroll
        for (int l = 0; l < 4; ++l) {
            const int f = tid + l * 256;      // float4 index in [0,1024)
            const int r = f >> 3;             // tile row 0..127
            const int c = (f & 7) << 2;       // k offset 0,4,...,28
            const float4 av = *(const float4*)&X[(size_t)(m0 + r) * K + k0 + c];
            const float4 bv = *(const float4*)&Wm[(size_t)(n0 + r) * K + k0 + c];
            const int rg = r >> 2, ri = r & 3;
#pragma unroll
            for (int cc = 0; cc < 4; ++cc) {
                const int kk = c + cc;
                const int sw = ((rg ^ kk) & 31) * 4 + ri;
                As[kk][sw] = ((const float*)&av)[cc];
                Bs[kk][sw] = ((const float*)&bv)[cc];
            }
        }
        __syncthreads();

#pragma unroll
        for (int kk = 0; kk < 32; ++kk) {
            float a_[8], b_[8];
            *(float4*)&a_[0] = *(const float4*)&As[kk][((ty        ^ kk) & 31) * 4];
            *(float4*)&a_[4] = *(const float4*)&As[kk][(((ty + 16) ^ kk) & 31) * 4];
            *(float4*)&b_[0] = *(const float4*)&Bs[kk][((tx        ^ kk) & 31) * 4];
            *(float4*)&b_[4] = *(const float4*)&Bs[kk][(((tx + 16) ^ kk) & 31) * 4];
#pragma unroll
            for (int ih = 0; ih < 2; ++ih)
#pragma unroll
                for (int jh = 0; jh < 2; ++jh)
#pragma unroll
                    for (int i = 0; i < 4; ++i)
#pragma unroll
                        for (int j = 0; j < 4; ++j)
                            acc[ih][jh][i][j] =
                                fmaf(a_[ih * 4 + i], b_[jh * 4 + j], acc[ih][jh][i][j]);
        }
        __syncthreads();
    }

#pragma unroll
    for (int ih = 0; ih < 2; ++ih)
#pragma unroll
        for (int i = 0; i < 4; ++i)
#pragma unroll
            for (int jh = 0; jh < 2; ++jh) {
                float4 o;
                ((float*)&o)[0] = acc[ih][jh][i][0];
                ((float*)&o)[1] = acc[ih][jh][i][1];
                ((float*)&o)[2] = acc[ih][jh][i][2];
                ((float*)&o)[3] = acc[ih][jh][i][3];
                *(float4*)&Ym[(size_t)(m0 + ih * 64 + ty * 4 + i) * N +
                              n0 + jh * 64 + tx * 4] = o;
            }
}

// ---------------------------------------------------------------------------
// Sliding-window causal attention, flash-style online softmax.
// One block per (b, h, 64-query tile). Key tiles of 64, at most 5 per block.
// 16x16-thread / 4x4-fragment structure, XOR-swizzled LDS.
// ---------------------------------------------------------------------------
__global__ __launch_bounds__(256, 2) void attn_win(
    const float* __restrict__ Q, const float* __restrict__ K,
    const float* __restrict__ V, float* __restrict__ O)
{
    const int b = blockIdx.z, h = blockIdx.y;
    const int q0 = blockIdx.x * 64;
    const int tid = threadIdx.x;
    const int tx = tid & 15, ty = tid >> 4;

    __shared__ float Qs[64][64];   // [d][q-row], swizzled
    __shared__ float Ks[64][64];   // [d][k-row], swizzled
    __shared__ float Vs[64][64];   // [k-row][d], natural
    __shared__ float Ps[64][64];   // [k-row][q-row], swizzled

    const float* qbase = Q + (size_t)(b * T_) * C_ + h * D_;
    const float* kbase = K + (size_t)(b * T_) * C_ + h * D_;
    const float* vbase = V + (size_t)(b * T_) * C_ + h * D_;

    // Load Q tile (64 rows x 64 d), transpose to d-major with swizzle.
#pragma unroll
    for (int l = 0; l < 4; ++l) {
        const int f = tid + l * 256;     // float4 idx in [0,1024)
        const int r = f >> 4;            // row 0..63
        const int c = (f & 15) << 2;     // d 0..60
        const float4 qv = *(const float4*)&qbase[(size_t)(q0 + r) * C_ + c];
        const int cb = r >> 2, ci = r & 3;
#pragma unroll
        for (int cc = 0; cc < 4; ++cc) {
            const int d = c + cc;
            Qs[d][((cb ^ (d >> 2)) & 15) * 4 + ci] = ((const float*)&qv)[cc];
        }
    }

    float m_run[4], l_run[4], oacc[4][4] = {};
#pragma unroll
    for (int i = 0; i < 4; ++i) { m_run[i] = -1e30f; l_run[i] = 0.f; }

    __syncthreads();   // Qs ready

    const int kt_lo = (q0 - W_ > 0) ? (q0 - W_) : 0;
    for (int kt = kt_lo; kt <= q0; kt += 64) {
        // Stage K (transposed+swizzled) and V (natural) tiles.
#pragma unroll
        for (int l = 0; l < 4; ++l) {
            const int f = tid + l * 256;
            const int r = f >> 4;
            const int c = (f & 15) << 2;
            const float4 kv = *(const float4*)&kbase[(size_t)(kt + r) * C_ + c];
            const float4 vv = *(const float4*)&vbase[(size_t)(kt + r) * C_ + c];
            const int cb = r >> 2, ci = r & 3;
#pragma unroll
            for (int cc = 0; cc < 4; ++cc) {
                const int d = c + cc;
                Ks[d][((cb ^ (d >> 2)) & 15) * 4 + ci] = ((const float*)&kv)[cc];
            }
            *(float4*)&Vs[r][c] = vv;
        }
        __syncthreads();

        // S = Q K^T  (4x4 fragment per thread)
        float s[4][4] = {};
#pragma unroll
        for (int d = 0; d < 64; ++d) {
            const float4 qf = *(const float4*)&Qs[d][((ty ^ (d >> 2)) & 15) * 4];
            const float4 kf = *(const float4*)&Ks[d][((tx ^ (d >> 2)) & 15) * 4];
            const float* a = (const float*)&qf;
            const float* bq = (const float*)&kf;
#pragma unroll
            for (int i = 0; i < 4; ++i)
#pragma unroll
                for (int j = 0; j < 4; ++j)
                    s[i][j] = fmaf(a[i], bq[j], s[i][j]);
        }

        // Mask + online softmax (row reduction across the 16 tx lanes).
#pragma unroll
        for (int i = 0; i < 4; ++i) {
            const int gi = q0 + ty * 4 + i;
            bool ok[4];
            float sv[4];
            float mi = -1e30f;
#pragma unroll
            for (int j = 0; j < 4; ++j) {
                const int gj = kt + tx * 4 + j;
                ok[j] = (gj <= gi) && (gi - gj < W_);
                sv[j] = ok[j] ? s[i][j] * SCALE_ : -1e30f;
                mi = fmaxf(mi, sv[j]);
            }
#pragma unroll
            for (int off = 1; off < 16; off <<= 1)
                mi = fmaxf(mi, __shfl_xor(mi, off));

            const float mnew = fmaxf(m_run[i], mi);
            float p[4];
            float rsum = 0.f;
#pragma unroll
            for (int j = 0; j < 4; ++j) {
                p[j] = ok[j] ? __expf(sv[j] - mnew) : 0.f;
                rsum += p[j];
            }
#pragma unroll
            for (int off = 1; off < 16; off <<= 1)
                rsum += __shfl_xor(rsum, off);

            const float fac = __expf(m_run[i] - mnew);
            l_run[i] = l_run[i] * fac + rsum;
#pragma unroll
            for (int j = 0; j < 4; ++j) oacc[i][j] *= fac;
            m_run[i] = mnew;

            // P transposed into LDS: Ps[key][q-row], swizzled (key>>2 == tx).
#pragma unroll
            for (int j = 0; j < 4; ++j)
                Ps[tx * 4 + j][((ty ^ tx) & 15) * 4 + i] = p[j];
        }
        __syncthreads();   // Ps complete

        // O += P V
#pragma unroll
        for (int kk = 0; kk < 64; ++kk) {
            const float4 pf = *(const float4*)&Ps[kk][((ty ^ (kk >> 2)) & 15) * 4];
            const float4 vf = *(const float4*)&Vs[kk][tx * 4];
            const float* p = (const float*)&pf;
            const float* vv = (const float*)&vf;
#pragma unroll
            for (int i = 0; i < 4; ++i)
#pragma unroll
                for (int j = 0; j < 4; ++j)
                    oacc[i][j] = fmaf(p[i], vv[j], oacc[i][j]);
        }
        __syncthreads();   // done with Ks/Vs/Ps before next stage
    }

    // Normalize and store: O[(b*T + q0+row), h*64 + d]
#pragma unroll
    for (int i = 0; i < 4; ++i) {
        const float inv = 1.f / l_run[i];
        float4 o;
        ((float*)&o)[0] = oacc[i][0] * inv;
        ((float*)&o)[1] = oacc[i][1] * inv;
        ((float*)&o)[2] = oacc[i][2] * inv;
        ((float*)&o)[3] = oacc[i][3] * inv;
        *(float4*)&O[(size_t)(b * T_ + q0 + ty * 4 + i) * C_ + h * D_ + tx * 4] = o;
    }
}

// ---------------------------------------------------------------------------
extern "C" void kernel_launch(void* const* d_in, const int* in_sizes, int n_in,
                              void* d_out, int out_size, void* d_ws, size_t ws_size,
                              hipStream_t stream)
{
    const float* x  = (const float*)d_in[0];
    const float* wq = (const float*)d_in[1];
    const float* wk = (const float*)d_in[2];
    const float* wv = (const float*)d_in[3];
    const float* wo = (const float*)d_in[4];
    float* out = (float*)d_out;

    float* q = (float*)d_ws;                 // [M_, C_]
    float* k = q + (size_t)M_ * C_;          // [M_, C_]
    float* v = k + (size_t)M_ * C_;          // [M_, C_]
    float* a = q;                            // attention out aliases q (safe:
                                             // each attn block consumes its own
                                             // q-region into LDS before writing)

    const dim3 blk(256);

    // Fused QKV projections: z picks (wq,q) / (wk,k) / (wv,v).
    gemm_xwT<<<dim3(C_ / 128, M_ / 128, 3), blk, 0, stream>>>(
        x, wq, wk, wv, q, k, v, M_, C_, C_);

    // Windowed attention.
    attn_win<<<dim3(T_ / 64, H_, B_), blk, 0, stream>>>(q, k, v, a);

    // Output projection.
    gemm_xwT<<<dim3(C_ / 128, M_ / 128, 1), blk, 0, stream>>>(
        a, wo, wo, wo, out, out, out, M_, C_, C_);
}

// Round 5
// 237.128 us; speedup vs baseline: 6.3326x; 6.3326x over previous
//
#include <hip/hip_runtime.h>
#include <hip/hip_bf16.h>

// Problem constants (B,T,C,H,W,D) from the reference.
constexpr int B_ = 2, T_ = 2048, C_ = 1024, H_ = 16, W_ = 256, D_ = 64;
constexpr int M_ = B_ * T_;            // 4096 rows
constexpr float SCALE_ = 0.125f;       // 1/sqrt(64)

typedef __attribute__((ext_vector_type(8))) short bf16x8;
typedef __attribute__((ext_vector_type(4))) float f32x4;

static __device__ __forceinline__ unsigned short f2bf(float x) {
    __hip_bfloat16 h = __float2bfloat16(x);
    return *reinterpret_cast<unsigned short*>(&h);
}

// ---------------------------------------------------------------------------
// Cast fp32 -> bf16 for x and the four weights. z selects the array.
// ---------------------------------------------------------------------------
__global__ void cast_to_bf16(
    const float* __restrict__ s0, const float* __restrict__ s1,
    const float* __restrict__ s2, const float* __restrict__ s3,
    const float* __restrict__ s4,
    unsigned short* __restrict__ d0, unsigned short* __restrict__ d1,
    unsigned short* __restrict__ d2, unsigned short* __restrict__ d3,
    unsigned short* __restrict__ d4,
    int n0, int n1, int n2, int n3, int n4)
{
    const int z = blockIdx.z;
    const float* s = (z==0)?s0:(z==1)?s1:(z==2)?s2:(z==3)?s3:s4;
    unsigned short* d = (z==0)?d0:(z==1)?d1:(z==2)?d2:(z==3)?d3:d4;
    const int n8 = ((z==0)?n0:(z==1)?n1:(z==2)?n2:(z==3)?n3:n4) >> 3;
    for (int i = blockIdx.x * blockDim.x + threadIdx.x; i < n8;
         i += gridDim.x * blockDim.x) {
        const float4 f0 = *(const float4*)&s[(size_t)i * 8];
        const float4 f1 = *(const float4*)&s[(size_t)i * 8 + 4];
        uint4 o;
        o.x = (unsigned)f2bf(f0.x) | ((unsigned)f2bf(f0.y) << 16);
        o.y = (unsigned)f2bf(f0.z) | ((unsigned)f2bf(f0.w) << 16);
        o.z = (unsigned)f2bf(f1.x) | ((unsigned)f2bf(f1.y) << 16);
        o.w = (unsigned)f2bf(f1.z) | ((unsigned)f2bf(f1.w) << 16);
        *(uint4*)&d[(size_t)i * 8] = o;
    }
}

// ---------------------------------------------------------------------------
// bf16 MFMA GEMM: Y[m,n] = sum_k A[m,k] * Wt[n,k]   (A @ W.T)
// A, W in bf16 row-major; Y fp32. 128x128 tile, BK=32, 256 threads = 4 waves
// in 2x2, each wave a 64x64 sub-tile = 4x4 frags of mfma_f32_16x16x32_bf16.
// C/D layout per frag: col = lane&15, row = (lane>>4)*4 + reg  [m89].
// blockIdx.z selects weight/output pair (fused QKV).
// ---------------------------------------------------------------------------
__global__ __launch_bounds__(256, 2) void gemm_bf16(
    const unsigned short* __restrict__ A,
    const unsigned short* __restrict__ B0, const unsigned short* __restrict__ B1,
    const unsigned short* __restrict__ B2,
    float* __restrict__ Y0, float* __restrict__ Y1, float* __restrict__ Y2,
    int M, int N, int K)
{
    const unsigned short* Bm = (blockIdx.z == 0) ? B0 : (blockIdx.z == 1) ? B1 : B2;
    float*                Ym = (blockIdx.z == 0) ? Y0 : (blockIdx.z == 1) ? Y1 : Y2;

    __shared__ unsigned short As[128 * 32];   // [row][k] linear bf16
    __shared__ unsigned short Bs[128 * 32];

    const int tid = threadIdx.x;
    const int lane = tid & 63, wave = tid >> 6;
    const int m0 = blockIdx.y * 128, n0 = blockIdx.x * 128;
    const int wm = (wave >> 1) * 64, wn = (wave & 1) * 64;
    const int row16 = lane & 15, kg = lane >> 4;

    f32x4 acc[4][4] = {};

    // Staging: 16B chunk c (c=0..511): row = c>>2, k-offset = (c&3)*8.
    const int c0 = tid, c1 = tid + 256;
    const size_t ar0 = (size_t)(m0 + (c0 >> 2)) * K + (c0 & 3) * 8;
    const size_t ar1 = (size_t)(m0 + (c1 >> 2)) * K + (c1 & 3) * 8;
    const size_t br0 = (size_t)(n0 + (c0 >> 2)) * K + (c0 & 3) * 8;
    const size_t br1 = (size_t)(n0 + (c1 >> 2)) * K + (c1 & 3) * 8;

    for (int k0 = 0; k0 < K; k0 += 32) {
        const uint4 a0 = *(const uint4*)&A[ar0 + k0];
        const uint4 a1 = *(const uint4*)&A[ar1 + k0];
        const uint4 b0 = *(const uint4*)&Bm[br0 + k0];
        const uint4 b1 = *(const uint4*)&Bm[br1 + k0];
        __syncthreads();                 // prev iteration's ds_reads done
        *(uint4*)&As[c0 * 8] = a0;
        *(uint4*)&As[c1 * 8] = a1;
        *(uint4*)&Bs[c0 * 8] = b0;
        *(uint4*)&Bs[c1 * 8] = b1;
        __syncthreads();                 // tiles ready

        bf16x8 af[4], bfr[4];
#pragma unroll
        for (int f = 0; f < 4; ++f) {
            // A-frag: lane holds A[row16][kg*8 .. +7]; B-frag symmetric
            af[f]  = *(const bf16x8*)&As[(wm + f * 16 + row16) * 32 + kg * 8];
            bfr[f] = *(const bf16x8*)&Bs[(wn + f * 16 + row16) * 32 + kg * 8];
        }
#pragma unroll
        for (int i = 0; i < 4; ++i)
#pragma unroll
            for (int j = 0; j < 4; ++j)
                acc[i][j] = __builtin_amdgcn_mfma_f32_16x16x32_bf16(
                    af[i], bfr[j], acc[i][j], 0, 0, 0);
    }

    const int orow = (lane >> 4) * 4, ocol = lane & 15;
#pragma unroll
    for (int i = 0; i < 4; ++i)
#pragma unroll
        for (int j = 0; j < 4; ++j)
#pragma unroll
            for (int r = 0; r < 4; ++r)
                Ym[(size_t)(m0 + wm + i * 16 + orow + r) * N +
                   n0 + wn + j * 16 + ocol] = acc[i][j][r];
}

// ---------------------------------------------------------------------------
// Sliding-window causal attention, flash-style online softmax (fp32 VALU).
// One block per (b, h, 64-query tile). Key tiles of 64, at most 5 per block.
// Inner 64-iter loops capped at unroll 4 (full unroll spilled -> 3.2 GB HBM).
// Output written as bf16 for the bf16 o-proj GEMM.
// ---------------------------------------------------------------------------
__global__ __launch_bounds__(256, 2) void attn_win(
    const float* __restrict__ Q, const float* __restrict__ K,
    const float* __restrict__ V, unsigned short* __restrict__ O)
{
    const int b = blockIdx.z, h = blockIdx.y;
    const int q0 = blockIdx.x * 64;
    const int tid = threadIdx.x;
    const int tx = tid & 15, ty = tid >> 4;

    __shared__ float Qs[64][64];   // [d][q-row], swizzled
    __shared__ float Ks[64][64];   // [d][k-row], swizzled
    __shared__ float Vs[64][64];   // [k-row][d], natural
    __shared__ float Ps[64][64];   // [k-row][q-row], swizzled

    const float* qbase = Q + (size_t)(b * T_) * C_ + h * D_;
    const float* kbase = K + (size_t)(b * T_) * C_ + h * D_;
    const float* vbase = V + (size_t)(b * T_) * C_ + h * D_;

    // Load Q tile (64 rows x 64 d), transpose to d-major with swizzle.
#pragma unroll
    for (int l = 0; l < 4; ++l) {
        const int f = tid + l * 256;     // float4 idx in [0,1024)
        const int r = f >> 4;            // row 0..63
        const int c = (f & 15) << 2;     // d 0..60
        const float4 qv = *(const float4*)&qbase[(size_t)(q0 + r) * C_ + c];
        const int cb = r >> 2, ci = r & 3;
#pragma unroll
        for (int cc = 0; cc < 4; ++cc) {
            const int d = c + cc;
            Qs[d][((cb ^ (d >> 2)) & 15) * 4 + ci] = ((const float*)&qv)[cc];
        }
    }

    float m_run[4], l_run[4], oacc[4][4] = {};
#pragma unroll
    for (int i = 0; i < 4; ++i) { m_run[i] = -1e30f; l_run[i] = 0.f; }

    __syncthreads();   // Qs ready

    const int kt_lo = (q0 - W_ > 0) ? (q0 - W_) : 0;
    for (int kt = kt_lo; kt <= q0; kt += 64) {
        // Stage K (transposed+swizzled) and V (natural) tiles.
#pragma unroll
        for (int l = 0; l < 4; ++l) {
            const int f = tid + l * 256;
            const int r = f >> 4;
            const int c = (f & 15) << 2;
            const float4 kv = *(const float4*)&kbase[(size_t)(kt + r) * C_ + c];
            const float4 vv = *(const float4*)&vbase[(size_t)(kt + r) * C_ + c];
            const int cb = r >> 2, ci = r & 3;
#pragma unroll
            for (int cc = 0; cc < 4; ++cc) {
                const int d = c + cc;
                Ks[d][((cb ^ (d >> 2)) & 15) * 4 + ci] = ((const float*)&kv)[cc];
            }
            *(float4*)&Vs[r][c] = vv;
        }
        __syncthreads();

        // S = Q K^T  (4x4 fragment per thread) — unroll capped (spill fix)
        float s[4][4] = {};
#pragma unroll 4
        for (int d = 0; d < 64; ++d) {
            const float4 qf = *(const float4*)&Qs[d][((ty ^ (d >> 2)) & 15) * 4];
            const float4 kf = *(const float4*)&Ks[d][((tx ^ (d >> 2)) & 15) * 4];
            const float* a = (const float*)&qf;
            const float* bq = (const float*)&kf;
#pragma unroll
            for (int i = 0; i < 4; ++i)
#pragma unroll
                for (int j = 0; j < 4; ++j)
                    s[i][j] = fmaf(a[i], bq[j], s[i][j]);
        }

        // Mask + online softmax (row reduction across the 16 tx lanes).
#pragma unroll
        for (int i = 0; i < 4; ++i) {
            const int gi = q0 + ty * 4 + i;
            bool ok[4];
            float sv[4];
            float mi = -1e30f;
#pragma unroll
            for (int j = 0; j < 4; ++j) {
                const int gj = kt + tx * 4 + j;
                ok[j] = (gj <= gi) && (gi - gj < W_);
                sv[j] = ok[j] ? s[i][j] * SCALE_ : -1e30f;
                mi = fmaxf(mi, sv[j]);
            }
#pragma unroll
            for (int off = 1; off < 16; off <<= 1)
                mi = fmaxf(mi, __shfl_xor(mi, off));

            const float mnew = fmaxf(m_run[i], mi);
            float p[4];
            float rsum = 0.f;
#pragma unroll
            for (int j = 0; j < 4; ++j) {
                p[j] = ok[j] ? __expf(sv[j] - mnew) : 0.f;
                rsum += p[j];
            }
#pragma unroll
            for (int off = 1; off < 16; off <<= 1)
                rsum += __shfl_xor(rsum, off);

            const float fac = __expf(m_run[i] - mnew);
            l_run[i] = l_run[i] * fac + rsum;
#pragma unroll
            for (int j = 0; j < 4; ++j) oacc[i][j] *= fac;
            m_run[i] = mnew;

            // P transposed into LDS: Ps[key][q-row], swizzled (key>>2 == tx).
#pragma unroll
            for (int j = 0; j < 4; ++j)
                Ps[tx * 4 + j][((ty ^ tx) & 15) * 4 + i] = p[j];
        }
        __syncthreads();   // Ps complete

        // O += P V — unroll capped (spill fix)
#pragma unroll 4
        for (int kk = 0; kk < 64; ++kk) {
            const float4 pf = *(const float4*)&Ps[kk][((ty ^ (kk >> 2)) & 15) * 4];
            const float4 vf = *(const float4*)&Vs[kk][tx * 4];
            const float* p = (const float*)&pf;
            const float* vv = (const float*)&vf;
#pragma unroll
            for (int i = 0; i < 4; ++i)
#pragma unroll
                for (int j = 0; j < 4; ++j)
                    oacc[i][j] = fmaf(p[i], vv[j], oacc[i][j]);
        }
        __syncthreads();   // done with Ks/Vs/Ps before next stage
    }

    // Normalize and store as bf16: O[(b*T + q0+row), h*64 + d]
#pragma unroll
    for (int i = 0; i < 4; ++i) {
        const float inv = 1.f / l_run[i];
        uint2 o;
        o.x = (unsigned)f2bf(oacc[i][0] * inv) | ((unsigned)f2bf(oacc[i][1] * inv) << 16);
        o.y = (unsigned)f2bf(oacc[i][2] * inv) | ((unsigned)f2bf(oacc[i][3] * inv) << 16);
        *(uint2*)&O[(size_t)(b * T_ + q0 + ty * 4 + i) * C_ + h * D_ + tx * 4] = o;
    }
}

// ---------------------------------------------------------------------------
extern "C" void kernel_launch(void* const* d_in, const int* in_sizes, int n_in,
                              void* d_out, int out_size, void* d_ws, size_t ws_size,
                              hipStream_t stream)
{
    const float* x  = (const float*)d_in[0];
    const float* wq = (const float*)d_in[1];
    const float* wk = (const float*)d_in[2];
    const float* wv = (const float*)d_in[3];
    const float* wo = (const float*)d_in[4];
    float* out = (float*)d_out;

    // Workspace layout (~64 MB total)
    float* q = (float*)d_ws;                        // [M_, C_] fp32
    float* k = q + (size_t)M_ * C_;                 // [M_, C_] fp32
    float* v = k + (size_t)M_ * C_;                 // [M_, C_] fp32
    unsigned short* xb  = (unsigned short*)(v + (size_t)M_ * C_);  // [M_, C_] bf16
    unsigned short* wqb = xb  + (size_t)M_ * C_;    // [C_, C_] bf16
    unsigned short* wkb = wqb + (size_t)C_ * C_;
    unsigned short* wvb = wkb + (size_t)C_ * C_;
    unsigned short* wob = wvb + (size_t)C_ * C_;
    // Attention output (bf16) reuses xb — x_bf16 is dead after the QKV GEMM.
    unsigned short* ab = xb;

    // 1. Cast inputs to bf16.
    cast_to_bf16<<<dim3(1024, 1, 5), 256, 0, stream>>>(
        x, wq, wk, wv, wo, xb, wqb, wkb, wvb, wob,
        M_ * C_, C_ * C_, C_ * C_, C_ * C_, C_ * C_);

    // 2. Fused QKV projections (bf16 MFMA, fp32 out).
    gemm_bf16<<<dim3(C_ / 128, M_ / 128, 3), 256, 0, stream>>>(
        xb, wqb, wkb, wvb, q, k, v, M_, C_, C_);

    // 3. Windowed attention (fp32), bf16 out.
    attn_win<<<dim3(T_ / 64, H_, B_), 256, 0, stream>>>(q, k, v, ab);

    // 4. Output projection (bf16 MFMA, fp32 out).
    gemm_bf16<<<dim3(C_ / 128, M_ / 128, 1), 256, 0, stream>>>(
        ab, wob, wob, wob, out, out, out, M_, C_, C_);
}

// Round 6
// 173.293 us; speedup vs baseline: 8.6653x; 1.3684x over previous
//
#include <hip/hip_runtime.h>
#include <hip/hip_bf16.h>

// Problem constants (B,T,C,H,W,D) from the reference.
constexpr int B_ = 2, T_ = 2048, C_ = 1024, H_ = 16, W_ = 256, D_ = 64;
constexpr int M_ = B_ * T_;            // 4096 rows
constexpr float SCALE_ = 0.125f;       // 1/sqrt(64)

typedef __attribute__((ext_vector_type(8))) short bf16x8;
typedef __attribute__((ext_vector_type(4))) float f32x4;
typedef unsigned short ushort_t;

static __device__ __forceinline__ unsigned short f2bf(float x) {
    __hip_bfloat16 h = __float2bfloat16(x);
    return *reinterpret_cast<unsigned short*>(&h);
}

// ---------------------------------------------------------------------------
// Cast fp32 -> bf16 for x and the four weights. z selects the array.
// ---------------------------------------------------------------------------
__global__ void cast_to_bf16(
    const float* __restrict__ s0, const float* __restrict__ s1,
    const float* __restrict__ s2, const float* __restrict__ s3,
    const float* __restrict__ s4,
    ushort_t* __restrict__ d0, ushort_t* __restrict__ d1,
    ushort_t* __restrict__ d2, ushort_t* __restrict__ d3,
    ushort_t* __restrict__ d4,
    int n0, int n1, int n2, int n3, int n4)
{
    const int z = blockIdx.z;
    const float* s = (z==0)?s0:(z==1)?s1:(z==2)?s2:(z==3)?s3:s4;
    ushort_t* d = (z==0)?d0:(z==1)?d1:(z==2)?d2:(z==3)?d3:d4;
    const int n8 = ((z==0)?n0:(z==1)?n1:(z==2)?n2:(z==3)?n3:n4) >> 3;
    for (int i = blockIdx.x * blockDim.x + threadIdx.x; i < n8;
         i += gridDim.x * blockDim.x) {
        const float4 f0 = *(const float4*)&s[(size_t)i * 8];
        const float4 f1 = *(const float4*)&s[(size_t)i * 8 + 4];
        uint4 o;
        o.x = (unsigned)f2bf(f0.x) | ((unsigned)f2bf(f0.y) << 16);
        o.y = (unsigned)f2bf(f0.z) | ((unsigned)f2bf(f0.w) << 16);
        o.z = (unsigned)f2bf(f1.x) | ((unsigned)f2bf(f1.y) << 16);
        o.w = (unsigned)f2bf(f1.z) | ((unsigned)f2bf(f1.w) << 16);
        *(uint4*)&d[(size_t)i * 8] = o;
    }
}

// ---------------------------------------------------------------------------
// bf16 MFMA GEMM: Y[m,n] = sum_k A[m,k] * Wt[n,k]   (A @ W.T)
// 128x128 tile, BK=32, 4 waves in 2x2, 4x4 frags of mfma_f32_16x16x32_bf16.
// BF16OUT=true -> Y is bf16 (scalar stores); false -> fp32.
// ---------------------------------------------------------------------------
template<bool BF16OUT>
__global__ __launch_bounds__(256, 2) void gemm_bf16(
    const ushort_t* __restrict__ A,
    const ushort_t* __restrict__ B0, const ushort_t* __restrict__ B1,
    const ushort_t* __restrict__ B2,
    void* __restrict__ Y0v, void* __restrict__ Y1v, void* __restrict__ Y2v,
    int M, int N, int K)
{
    const ushort_t* Bm = (blockIdx.z == 0) ? B0 : (blockIdx.z == 1) ? B1 : B2;
    void*           Ymv = (blockIdx.z == 0) ? Y0v : (blockIdx.z == 1) ? Y1v : Y2v;

    __shared__ __align__(16) ushort_t As[128 * 32];   // [row][k] linear bf16
    __shared__ __align__(16) ushort_t Bs[128 * 32];

    const int tid = threadIdx.x;
    const int lane = tid & 63, wave = tid >> 6;
    const int m0 = blockIdx.y * 128, n0 = blockIdx.x * 128;
    const int wm = (wave >> 1) * 64, wn = (wave & 1) * 64;
    const int row16 = lane & 15, kg = lane >> 4;

    f32x4 acc[4][4] = {};

    // Staging: 16B chunk c (c=0..511): row = c>>2, k-offset = (c&3)*8.
    const int c0 = tid, c1 = tid + 256;
    const size_t ar0 = (size_t)(m0 + (c0 >> 2)) * K + (c0 & 3) * 8;
    const size_t ar1 = (size_t)(m0 + (c1 >> 2)) * K + (c1 & 3) * 8;
    const size_t br0 = (size_t)(n0 + (c0 >> 2)) * K + (c0 & 3) * 8;
    const size_t br1 = (size_t)(n0 + (c1 >> 2)) * K + (c1 & 3) * 8;

    for (int k0 = 0; k0 < K; k0 += 32) {
        const uint4 a0 = *(const uint4*)&A[ar0 + k0];
        const uint4 a1 = *(const uint4*)&A[ar1 + k0];
        const uint4 b0 = *(const uint4*)&Bm[br0 + k0];
        const uint4 b1 = *(const uint4*)&Bm[br1 + k0];
        __syncthreads();                 // prev iteration's ds_reads done
        *(uint4*)&As[c0 * 8] = a0;
        *(uint4*)&As[c1 * 8] = a1;
        *(uint4*)&Bs[c0 * 8] = b0;
        *(uint4*)&Bs[c1 * 8] = b1;
        __syncthreads();                 // tiles ready

        bf16x8 af[4], bfr[4];
#pragma unroll
        for (int f = 0; f < 4; ++f) {
            af[f]  = *(const bf16x8*)&As[(wm + f * 16 + row16) * 32 + kg * 8];
            bfr[f] = *(const bf16x8*)&Bs[(wn + f * 16 + row16) * 32 + kg * 8];
        }
#pragma unroll
        for (int i = 0; i < 4; ++i)
#pragma unroll
            for (int j = 0; j < 4; ++j)
                acc[i][j] = __builtin_amdgcn_mfma_f32_16x16x32_bf16(
                    af[i], bfr[j], acc[i][j], 0, 0, 0);
    }

    const int orow = (lane >> 4) * 4, ocol = lane & 15;
    if constexpr (BF16OUT) {
        ushort_t* Ym = (ushort_t*)Ymv;
#pragma unroll
        for (int i = 0; i < 4; ++i)
#pragma unroll
            for (int j = 0; j < 4; ++j)
#pragma unroll
                for (int r = 0; r < 4; ++r)
                    Ym[(size_t)(m0 + wm + i * 16 + orow + r) * N +
                       n0 + wn + j * 16 + ocol] = f2bf(acc[i][j][r]);
    } else {
        float* Ym = (float*)Ymv;
#pragma unroll
        for (int i = 0; i < 4; ++i)
#pragma unroll
            for (int j = 0; j < 4; ++j)
#pragma unroll
                for (int r = 0; r < 4; ++r)
                    Ym[(size_t)(m0 + wm + i * 16 + orow + r) * N +
                       n0 + wn + j * 16 + ocol] = acc[i][j][r];
    }
}

// ---------------------------------------------------------------------------
// Sliding-window causal attention with bf16 MFMA for QK^T and PV.
// One block (4 waves) per (b, h, 64-query tile). Wave w owns q-row strip
// [w*16, w*16+16). Key tiles of 64, <=5 per block.
// LDS tiles (bf16, 8KB each): Ql[q][d], Kl[k][d], Vt[d][k], Pl[q][k],
// all granule-swizzled: granule(row, g) = row*8 + (g ^ (row&7)), granule=8elem.
// Frag convention identical to gemm_bf16 (HW-verified r5):
//   A/B-frag: lane holds [lane&15][(lane>>4)*8 +: 8] ; C/D: col=lane&15,
//   row=(lane>>4)*4+reg.  Y = A @ B^T:
//   S = Q @ K^T  (A=Ql rows, B=Kl rows — both [row][d], no transpose)
//   O = P @ V    (A=Pl rows [q][key], B=Vt rows [d][key] — V transposed)
// ---------------------------------------------------------------------------
__global__ __launch_bounds__(256, 4) void attn_win(
    const ushort_t* __restrict__ Q, const ushort_t* __restrict__ K,
    const ushort_t* __restrict__ V, ushort_t* __restrict__ O)
{
    const int b = blockIdx.z, h = blockIdx.y;
    const int q0 = blockIdx.x * 64;
    const int tid = threadIdx.x;
    const int lane = tid & 63, w = tid >> 6;
    const int r16 = lane & 15, kg = lane >> 4;

    __shared__ __align__(16) ushort_t Ql[64 * 64];
    __shared__ __align__(16) ushort_t Kl[64 * 64];
    __shared__ __align__(16) ushort_t Vt[64 * 64];
    __shared__ __align__(16) ushort_t Pl[64 * 64];

    const ushort_t* qbase = Q + (size_t)(b * T_) * C_ + h * D_;
    const ushort_t* kbase = K + (size_t)(b * T_) * C_ + h * D_;
    const ushort_t* vbase = V + (size_t)(b * T_) * C_ + h * D_;

    // ---- stage Q (64 rows x 64 d): granule id g: row=g>>3, gc=g&7.
#pragma unroll
    for (int l = 0; l < 2; ++l) {
        const int g = tid + l * 256;
        const int qr = g >> 3, gc = g & 7;
        const uint4 qv = *(const uint4*)&qbase[(size_t)(q0 + qr) * C_ + gc * 8];
        *(uint4*)&Ql[(qr * 8 + (gc ^ (qr & 7))) * 8] = qv;
    }

    const int qrow = w * 16 + r16;          // A-frag row (q) for this lane
    const int qloc_base = w * 16 + (lane >> 4) * 4;  // C/D rows base

    float m_run[4], l_run[4];
    f32x4 oacc[4] = {};                     // O strip: 4 d-frags x 4 rows
#pragma unroll
    for (int r = 0; r < 4; ++r) { m_run[r] = -1e30f; l_run[r] = 0.f; }

    const int kt_lo = (q0 - W_ > 0) ? (q0 - W_) : 0;
    for (int kt = kt_lo; kt <= q0; kt += 64) {
        __syncthreads();   // prior tile's reads done (first iter: Q staged)
        // ---- stage K tile [k][d] (b128) and V tile transposed -> Vt[d][k]
#pragma unroll
        for (int l = 0; l < 2; ++l) {
            const int g = tid + l * 256;
            const int kr = g >> 3, gc = g & 7;
            const uint4 kv = *(const uint4*)&kbase[(size_t)(kt + kr) * C_ + gc * 8];
            *(uint4*)&Kl[(kr * 8 + (gc ^ (kr & 7))) * 8] = kv;
            const uint4 vv = *(const uint4*)&vbase[(size_t)(kt + kr) * C_ + gc * 8];
            const ushort_t* vs = (const ushort_t*)&vv;
#pragma unroll
            for (int dd = 0; dd < 8; ++dd) {
                const int d = gc * 8 + dd;
                Vt[(d * 8 + ((kr >> 3) ^ (d & 7))) * 8 + (kr & 7)] = vs[dd];
            }
        }
        __syncthreads();   // tiles ready

        // ---- S = Q @ K^T : strip 16 q-rows x 64 k-cols, 4 col-frags
        bf16x8 aq0 = *(const bf16x8*)&Ql[(qrow * 8 + ((0 * 4 + kg) ^ (qrow & 7))) * 8];
        bf16x8 aq1 = *(const bf16x8*)&Ql[(qrow * 8 + ((1 * 4 + kg) ^ (qrow & 7))) * 8];
        f32x4 sacc[4] = {};
#pragma unroll
        for (int j = 0; j < 4; ++j) {
            const int krow = j * 16 + r16;
            const bf16x8 b0 = *(const bf16x8*)&Kl[(krow * 8 + ((0 * 4 + kg) ^ (krow & 7))) * 8];
            const bf16x8 b1 = *(const bf16x8*)&Kl[(krow * 8 + ((1 * 4 + kg) ^ (krow & 7))) * 8];
            sacc[j] = __builtin_amdgcn_mfma_f32_16x16x32_bf16(aq0, b0, sacc[j], 0, 0, 0);
            sacc[j] = __builtin_amdgcn_mfma_f32_16x16x32_bf16(aq1, b1, sacc[j], 0, 0, 0);
        }

        // ---- mask + online softmax; rows r: gi = q0 + qloc_base + r
#pragma unroll
        for (int r = 0; r < 4; ++r) {
            const int gi = q0 + qloc_base + r;
            float sv[4];
            bool ok[4];
            float mi = -1e30f;
#pragma unroll
            for (int j = 0; j < 4; ++j) {
                const int gj = kt + j * 16 + r16;
                ok[j] = (gj <= gi) && (gi - gj < W_);
                sv[j] = ok[j] ? sacc[j][r] * SCALE_ : -1e30f;
                mi = fmaxf(mi, sv[j]);
            }
#pragma unroll
            for (int off = 1; off < 16; off <<= 1)
                mi = fmaxf(mi, __shfl_xor(mi, off));

            const float mnew = fmaxf(m_run[r], mi);
            float rsum = 0.f;
            float p[4];
#pragma unroll
            for (int j = 0; j < 4; ++j) {
                p[j] = ok[j] ? __expf(sv[j] - mnew) : 0.f;
                rsum += p[j];
            }
#pragma unroll
            for (int off = 1; off < 16; off <<= 1)
                rsum += __shfl_xor(rsum, off);

            const float fac = __expf(m_run[r] - mnew);
            l_run[r] = l_run[r] * fac + rsum;
            m_run[r] = mnew;
#pragma unroll
            for (int jd = 0; jd < 4; ++jd) oacc[jd][r] *= fac;

            // P -> bf16 -> Pl[q][k] (own strip only; no cross-wave use)
            const int q = qloc_base + r;
#pragma unroll
            for (int j = 0; j < 4; ++j) {
                const int k = j * 16 + r16;
                Pl[(q * 8 + ((k >> 3) ^ (q & 7))) * 8 + (k & 7)] = f2bf(p[j]);
            }
        }

        // ---- O += P @ V : A = Pl strip, B = Vt
        const bf16x8 pa0 = *(const bf16x8*)&Pl[(qrow * 8 + ((0 * 4 + kg) ^ (qrow & 7))) * 8];
        const bf16x8 pa1 = *(const bf16x8*)&Pl[(qrow * 8 + ((1 * 4 + kg) ^ (qrow & 7))) * 8];
#pragma unroll
        for (int jd = 0; jd < 4; ++jd) {
            const int drow = jd * 16 + r16;
            const bf16x8 v0 = *(const bf16x8*)&Vt[(drow * 8 + ((0 * 4 + kg) ^ (drow & 7))) * 8];
            const bf16x8 v1 = *(const bf16x8*)&Vt[(drow * 8 + ((1 * 4 + kg) ^ (drow & 7))) * 8];
            oacc[jd] = __builtin_amdgcn_mfma_f32_16x16x32_bf16(pa0, v0, oacc[jd], 0, 0, 0);
            oacc[jd] = __builtin_amdgcn_mfma_f32_16x16x32_bf16(pa1, v1, oacc[jd], 0, 0, 0);
        }
    }

    // ---- normalize, store bf16: O[(b*T + q0 + qloc + r)][h*64 + jd*16 + col]
    ushort_t* obase = O + (size_t)(b * T_) * C_ + h * D_;
#pragma unroll
    for (int r = 0; r < 4; ++r) {
        const float inv = 1.f / l_run[r];
        const size_t row = (size_t)(q0 + qloc_base + r) * C_;
#pragma unroll
        for (int jd = 0; jd < 4; ++jd)
            obase[row + jd * 16 + r16] = f2bf(oacc[jd][r] * inv);
    }
}

// ---------------------------------------------------------------------------
extern "C" void kernel_launch(void* const* d_in, const int* in_sizes, int n_in,
                              void* d_out, int out_size, void* d_ws, size_t ws_size,
                              hipStream_t stream)
{
    const float* x  = (const float*)d_in[0];
    const float* wq = (const float*)d_in[1];
    const float* wk = (const float*)d_in[2];
    const float* wv = (const float*)d_in[3];
    const float* wo = (const float*)d_in[4];
    float* out = (float*)d_out;

    // Workspace layout (bf16 everywhere; ~40 MB)
    ushort_t* qb  = (ushort_t*)d_ws;                // [M_, C_] bf16
    ushort_t* kb  = qb  + (size_t)M_ * C_;
    ushort_t* vb  = kb  + (size_t)M_ * C_;
    ushort_t* xb  = vb  + (size_t)M_ * C_;          // [M_, C_] bf16
    ushort_t* wqb = xb  + (size_t)M_ * C_;          // [C_, C_] bf16
    ushort_t* wkb = wqb + (size_t)C_ * C_;
    ushort_t* wvb = wkb + (size_t)C_ * C_;
    ushort_t* wob = wvb + (size_t)C_ * C_;
    ushort_t* ab  = xb;   // attention out reuses xb (dead after QKV GEMM)

    // 1. Cast inputs to bf16.
    cast_to_bf16<<<dim3(1024, 1, 5), 256, 0, stream>>>(
        x, wq, wk, wv, wo, xb, wqb, wkb, wvb, wob,
        M_ * C_, C_ * C_, C_ * C_, C_ * C_, C_ * C_);

    // 2. Fused QKV projections (bf16 MFMA, bf16 out).
    gemm_bf16<true><<<dim3(C_ / 128, M_ / 128, 3), 256, 0, stream>>>(
        xb, wqb, wkb, wvb, qb, kb, vb, M_, C_, C_);

    // 3. Windowed attention (MFMA), bf16 out.
    attn_win<<<dim3(T_ / 64, H_, B_), 256, 0, stream>>>(qb, kb, vb, ab);

    // 4. Output projection (bf16 MFMA, fp32 out).
    gemm_bf16<false><<<dim3(C_ / 128, M_ / 128, 1), 256, 0, stream>>>(
        ab, wob, wob, wob, out, out, out, M_, C_, C_);
}